// Round 2
// baseline (424.857 us; speedup 1.0000x reference)
//
#include <hip/hip_runtime.h>
#include <hip/hip_bf16.h>
#include <stdint.h>

#define KTOT 8192
#define BM 16
#define BK 128
#define NIT (KTOT / BK)   // 64

typedef __attribute__((ext_vector_type(8))) __bf16 bf16x8;
typedef __attribute__((ext_vector_type(4))) float f32x4;

__device__ __forceinline__ unsigned short f2bf(float f) {
  union { float f; unsigned int u; } a;
  a.f = f;
  unsigned int r = (a.u + 0x7fffu + ((a.u >> 16) & 1u)) >> 16;
  return (unsigned short)r;
}

// x [8192][64] f32  ->  xt [64][8192] bf16 (transposed)
__global__ __launch_bounds__(256) void xpose_f32_bf16(const float* __restrict__ x,
                                                      __hip_bfloat16* __restrict__ xt) {
  __shared__ unsigned short tile[64][72];
  const int r0 = blockIdx.x * 64;
  const int t = threadIdx.x;
  const int a = t >> 4;          // 0..15
  const int c4 = (t & 15) * 4;   // 0..60
#pragma unroll
  for (int rep = 0; rep < 4; ++rep) {
    int r = a + rep * 16;
    float4 v = *reinterpret_cast<const float4*>(x + (size_t)(r0 + r) * 64 + c4);
    tile[c4 + 0][r] = f2bf(v.x);
    tile[c4 + 1][r] = f2bf(v.y);
    tile[c4 + 2][r] = f2bf(v.z);
    tile[c4 + 3][r] = f2bf(v.w);
  }
  __syncthreads();
#pragma unroll
  for (int rep = 0; rep < 4; ++rep) {
    int j = a + rep * 16;
    uint2 v = *reinterpret_cast<const uint2*>(&tile[j][c4]);
    *reinterpret_cast<uint2*>((unsigned short*)xt + (size_t)j * KTOT + r0 + c4) = v;
  }
}

// C[8192][BN] = A(f32 [8192][8192]) @ B, B given transposed bf16: BT[BN][8192].
// A staged reg->bf16->LDS (XOR swizzle); B fragments read DIRECTLY from global
// (L2-resident panel) into registers, double-buffered.
// BM=16, 512 threads (8 waves). BN=128: 8 col-waves. BN=64: 4 col-waves x 2 K-ways
// with LDS reduction at the end.
template <int BN>
__global__ __launch_bounds__(512, 4) void gemm_nt(
    const float* __restrict__ A, const __hip_bfloat16* __restrict__ BTv,
    float* __restrict__ out_lo, float* __restrict__ out_hi,
    const float* s_lo_ptr, const float* s_hi_ptr,
    const float* add_ptr, const float* add_s_ptr,
    __hip_bfloat16* bt_lo, __hip_bfloat16* bt_hi, int accum) {
  static_assert(BN == 64 || BN == 128, "");
  constexpr int NW_N = BN / 16;        // column waves: 8 or 4
  constexpr int KWAYS = 8 / NW_N;      // 1 or 2
  constexpr int KS_PER = 4 / KWAYS;    // K=32 slices per wave per tile: 4 or 2
  constexpr int SZ_A = BM * BK * 2;    // 4 KiB bf16
  __shared__ __align__(16) unsigned char smem[2 * SZ_A];

  const unsigned short* BT = (const unsigned short*)BTv;
  const int t = threadIdx.x;
  const int l = t & 63;
  const int w = t >> 6;
  const int r0 = blockIdx.x * BM;

  // ---- A staging: 16x128 f32 tile, 1 float4 per thread ----
  const int am = t >> 5;                  // row 0..15
  const int ac4 = t & 31;                 // float4 col 0..31
  const int goff_a = (r0 + am) * KTOT + ac4 * 4;
  const int loff_a = am * 256 + ((ac4 * 8) ^ ((am & 7) << 4));  // swizzled byte off

  // ---- wave/lane roles ----
  const int wn = w % NW_N;
  const int kw = w / NW_N;                // 0 (BN=128) or 0/1 (BN=64)
  const int lr = l & 15;
  const int g = l >> 4;
  const int col = wn * 16 + lr;           // output column / BT row
  const size_t bbase = (size_t)col * KTOT + kw * (KS_PER * 32) + g * 8;
  const int asw = (lr & 7) << 4;

  f32x4 acc = {0.f, 0.f, 0.f, 0.f};
  float4 av;
  bf16x8 Bf0[KS_PER], Bf1[KS_PER];

  unsigned char* lds0 = smem;
  unsigned char* lds1 = smem + SZ_A;

  auto loadA = [&](int k0) {
    av = *reinterpret_cast<const float4*>(A + goff_a + k0);
  };
  auto writeA = [&](unsigned char* ab) {
    union { unsigned short h[4]; uint2 v; } pk;
    pk.h[0] = f2bf(av.x);
    pk.h[1] = f2bf(av.y);
    pk.h[2] = f2bf(av.z);
    pk.h[3] = f2bf(av.w);
    *reinterpret_cast<uint2*>(ab + loff_a) = pk.v;
  };
  auto loadB = [&](bf16x8* Bf, int k0) {
#pragma unroll
    for (int ks = 0; ks < KS_PER; ++ks)
      Bf[ks] = *reinterpret_cast<const bf16x8*>(BT + bbase + k0 + ks * 32);
  };
  auto compute = [&](const unsigned char* ab, const bf16x8* Bf) {
#pragma unroll
    for (int ks = 0; ks < KS_PER; ++ks) {
      int ks_eff = kw * KS_PER + ks;
      bf16x8 af = *reinterpret_cast<const bf16x8*>(
          ab + lr * 256 + ((ks_eff * 64 + g * 16) ^ asw));
      acc = __builtin_amdgcn_mfma_f32_16x16x32_bf16(af, Bf[ks], acc, 0, 0, 0);
    }
  };

  // prologue: tile 0 into lds0 + B regs
  loadA(0);
  loadB(Bf0, 0);
  writeA(lds0);            // compiler inserts counted vmcnt for av
  __syncthreads();

#pragma unroll 1
  for (int it = 0; it < NIT; it += 2) {
    // even phase: compute tile it from lds0/Bf0, prefetch tile it+1
    if (it + 1 < NIT) { loadA((it + 1) * BK); loadB(Bf1, (it + 1) * BK); }
    compute(lds0, Bf0);
    if (it + 1 < NIT) writeA(lds1);
    __syncthreads();
    // odd phase: compute tile it+1 from lds1/Bf1, prefetch tile it+2
    if (it + 2 < NIT) { loadA((it + 2) * BK); loadB(Bf0, (it + 2) * BK); }
    compute(lds1, Bf1);
    if (it + 2 < NIT) writeA(lds0);
    __syncthreads();
  }

  // ---- K-ways reduction (BN=64 only) ----
  if constexpr (KWAYS == 2) {
    float* red = (float*)smem;           // 4 KiB: 4 waves x 64 lanes x 4 f32
    if (kw == 1)
      *reinterpret_cast<f32x4*>(red + (wn * 64 + l) * 4) = acc;
    __syncthreads();
    if (kw == 1) return;
    acc += *reinterpret_cast<f32x4*>(red + (wn * 64 + l) * 4);
  }

  // ---- epilogue ----
  const float s_lo = s_lo_ptr ? *s_lo_ptr : 0.f;
  const float s_hi = s_hi_ptr ? *s_hi_ptr : 0.f;
  const float was = add_s_ptr ? *add_s_ptr : 0.f;
  const int rbase = r0 + 4 * g;

  const bool hi = (BN == 128) && (col >= 64);
  const int col64 = hi ? (col - 64) : col;
  __hip_bfloat16* bt = hi ? bt_hi : bt_lo;
  if (bt) {  // raw C transposed as bf16: bt[col64][r]
    union { unsigned short h[4]; uint2 v; } pk;
#pragma unroll
    for (int i = 0; i < 4; ++i) pk.h[i] = f2bf(acc[i]);
    *reinterpret_cast<uint2*>((unsigned short*)bt + (size_t)col64 * KTOT + rbase) = pk.v;
  }
  float* op = hi ? out_hi : out_lo;
  if (op) {
    float s = hi ? s_hi : s_lo;
#pragma unroll
    for (int i = 0; i < 4; ++i) {
      int r = rbase + i;
      float v = s * acc[i];
      if (add_ptr) v = fmaf(was, add_ptr[(size_t)r * 64 + col64], v);
      if (accum) v += op[(size_t)r * 128 + col64];
      op[(size_t)r * 128 + col64] = v;
    }
  }
}

extern "C" void kernel_launch(void* const* d_in, const int* in_sizes, int n_in,
                              void* d_out, int out_size, void* d_ws, size_t ws_size,
                              hipStream_t stream) {
  const float* A_p = (const float*)d_in[0];
  const float* A_n = (const float*)d_in[1];
  const float* x_p = (const float*)d_in[2];
  const float* x_n = (const float*)d_in[3];
  const float* w_p = (const float*)d_in[4];  // [3]
  const float* w_n = (const float*)d_in[5];  // [3]
  float* out = (float*)d_out;                // [8192][128]

  // workspace: 5 MiB of bf16 transposed RHS panels
  __hip_bfloat16* B1T = (__hip_bfloat16*)d_ws;         // [128][8192]: rows 0-63 x_p^T, 64-127 x_n^T
  __hip_bfloat16* B2T = B1T + (size_t)128 * KTOT;      // [128][8192]: rows 0-63 P1^T, 64-127 T1^T
  __hip_bfloat16* B3T = B2T + (size_t)128 * KTOT;      // [64][8192]:  Y1^T

  xpose_f32_bf16<<<128, 256, 0, stream>>>(x_p, B1T);
  xpose_f32_bf16<<<128, 256, 0, stream>>>(x_n, B1T + (size_t)64 * KTOT);

  // GEMM1: [P1|Y1] = A_p @ [x_p|x_n]; out[:,0:64] = wp0*x_p + wp1*P1; emit P1^T, Y1^T
  gemm_nt<128><<<512, 512, 0, stream>>>(A_p, B1T, out, nullptr, w_p + 1, nullptr,
                                        x_p, w_p + 0, B2T, B3T, 0);
  // GEMM2: T1 = A_n @ x_n; out[:,64:128] = wn0*T1; emit T1^T
  gemm_nt<64><<<512, 512, 0, stream>>>(A_n, B1T + (size_t)64 * KTOT, out + 64, nullptr,
                                       w_n + 0, nullptr, nullptr, nullptr,
                                       B2T + (size_t)64 * KTOT, nullptr, 0);
  // GEMM3: [P2|T2] = A_p @ [P1|T1]; out[:,0:64] += wp2*P2; out[:,64:128] += wn1*T2
  gemm_nt<128><<<512, 512, 0, stream>>>(A_p, B2T, out, out + 64, w_p + 2, w_n + 1,
                                        nullptr, nullptr, nullptr, nullptr, 1);
  // GEMM4: T3 = A_n @ Y1; out[:,64:128] += wn2*T3
  gemm_nt<64><<<512, 512, 0, stream>>>(A_n, B3T, out + 64, nullptr, w_n + 2, nullptr,
                                       nullptr, nullptr, nullptr, nullptr, 1);
}

// Round 3
// 264.567 us; speedup vs baseline: 1.6059x; 1.6059x over previous
//
#include <hip/hip_runtime.h>
#include <hip/hip_bf16.h>
#include <stdint.h>

#define KTOT 8192
#define BM 64
#define BK 128
#define KSPLIT 2
#define KCHUNK (KTOT / KSPLIT)   // 4096
#define NIT (KCHUNK / BK)        // 32

typedef __attribute__((ext_vector_type(8))) __bf16 bf16x8;
typedef __attribute__((ext_vector_type(4))) float f32x4;

__device__ __forceinline__ unsigned short f2bf(float f) {
  union { float f; unsigned int u; } a;
  a.f = f;
  unsigned int r = (a.u + 0x7fffu + ((a.u >> 16) & 1u)) >> 16;
  return (unsigned short)r;
}

__device__ __forceinline__ uint2 pack4(f32x4 v) {
  union { unsigned short h[4]; uint2 u; } pk;
  pk.h[0] = f2bf(v[0]); pk.h[1] = f2bf(v[1]);
  pk.h[2] = f2bf(v[2]); pk.h[3] = f2bf(v[3]);
  return pk.u;
}

// x [8192][64] f32  ->  xt [64][8192] bf16 (transposed)
__global__ __launch_bounds__(256) void xpose_f32_bf16(const float* __restrict__ x,
                                                      __hip_bfloat16* __restrict__ xt) {
  __shared__ unsigned short tile[64][72];
  const int r0 = blockIdx.x * 64;
  const int t = threadIdx.x;
  const int a = t >> 4;
  const int c4 = (t & 15) * 4;
#pragma unroll
  for (int rep = 0; rep < 4; ++rep) {
    int r = a + rep * 16;
    float4 v = *reinterpret_cast<const float4*>(x + (size_t)(r0 + r) * 64 + c4);
    tile[c4 + 0][r] = f2bf(v.x);
    tile[c4 + 1][r] = f2bf(v.y);
    tile[c4 + 2][r] = f2bf(v.z);
    tile[c4 + 3][r] = f2bf(v.w);
  }
  __syncthreads();
#pragma unroll
  for (int rep = 0; rep < 4; ++rep) {
    int j = a + rep * 16;
    uint2 v = *reinterpret_cast<const uint2*>(&tile[j][c4]);
    *reinterpret_cast<uint2*>((unsigned short*)xt + (size_t)j * KTOT + r0 + c4) = v;
  }
}

// part[kc][col][row] (f32, [2][128][8192], COLUMN-major panels) = raw C partial of
// C = A(f32 [8192][8192]) @ B, B given transposed bf16 BT[128][8192].
// BM=64, 8 waves: wave w owns cols w*16..+15 and all 4 M-tiles (B frag reused 4x).
// grid 256: mblk = bid&127, kc = bid>>7 (K-range kc*4096..+4096).
__global__ __launch_bounds__(512) void gemm_part(
    const float* __restrict__ A, const __hip_bfloat16* __restrict__ BTv,
    float* __restrict__ part) {
  constexpr int SZ_A = BM * BK * 2;   // 16 KiB bf16
  __shared__ __align__(16) unsigned char smem[2 * SZ_A];
  const unsigned short* BT = (const unsigned short*)BTv;

  const int bid = blockIdx.x;
  const int kc = bid >> 7;
  const int mblk = bid & 127;
  const int r0 = mblk * BM;
  const int kbase = kc * KCHUNK;

  const int t = threadIdx.x;
  const int l = t & 63;
  const int w = t >> 6;

  // ---- A staging: 64x128 f32 tile, 4 float4 per thread ----
  size_t goff_a[4];
  int loff_a[4];
#pragma unroll
  for (int r = 0; r < 4; ++r) {
    int idx = t + r * 512;
    int m = idx >> 5, c4 = idx & 31;
    goff_a[r] = (size_t)(r0 + m) * KTOT + kbase + c4 * 4;
    loff_a[r] = m * 256 + ((c4 * 8) ^ ((m & 7) << 4));
  }

  const int lr = l & 15;
  const int g = l >> 4;
  const int col = w * 16 + lr;
  const size_t bbase = (size_t)col * KTOT + kbase + g * 8;
  const int asw = (lr & 7) << 4;

  f32x4 acc[4];
  const f32x4 fzero = {0.f, 0.f, 0.f, 0.f};
#pragma unroll
  for (int mt = 0; mt < 4; ++mt) acc[mt] = fzero;

  float4 av[4];
  bf16x8 Bf0[4], Bf1[4];
  unsigned char* lds0 = smem;
  unsigned char* lds1 = smem + SZ_A;

  auto loadA = [&](int k0) {
#pragma unroll
    for (int r = 0; r < 4; ++r)
      av[r] = *reinterpret_cast<const float4*>(A + goff_a[r] + k0);
  };
  auto writeA = [&](unsigned char* ab) {
#pragma unroll
    for (int r = 0; r < 4; ++r) {
      f32x4 v = {av[r].x, av[r].y, av[r].z, av[r].w};
      *reinterpret_cast<uint2*>(ab + loff_a[r]) = pack4(v);
    }
  };
  auto loadB = [&](bf16x8* Bf, int k0) {
#pragma unroll
    for (int ks = 0; ks < 4; ++ks)
      Bf[ks] = *reinterpret_cast<const bf16x8*>(BT + bbase + k0 + ks * 32);
  };
  auto compute = [&](const unsigned char* ab, const bf16x8* Bf) {
#pragma unroll
    for (int ks = 0; ks < 4; ++ks) {
#pragma unroll
      for (int mt = 0; mt < 4; ++mt) {
        bf16x8 af = *reinterpret_cast<const bf16x8*>(
            ab + (mt * 16 + lr) * 256 + ((ks * 64 + g * 16) ^ asw));
        acc[mt] = __builtin_amdgcn_mfma_f32_16x16x32_bf16(af, Bf[ks], acc[mt], 0, 0, 0);
      }
    }
  };

  // prologue
  loadA(0);
  loadB(Bf0, 0);
  writeA(lds0);
  __syncthreads();

#pragma unroll 1
  for (int it = 0; it < NIT; it += 2) {
    if (it + 1 < NIT) { loadA((it + 1) * BK); loadB(Bf1, (it + 1) * BK); }
    compute(lds0, Bf0);
    if (it + 1 < NIT) writeA(lds1);
    __syncthreads();
    if (it + 2 < NIT) { loadA((it + 2) * BK); loadB(Bf0, (it + 2) * BK); }
    compute(lds1, Bf1);
    if (it + 2 < NIT) writeA(lds0);
    __syncthreads();
  }

  // raw partial store: part[(kc*128+col)][r0 + mt*16 + g*4 .. +3]
  float* pp = part + (size_t)(kc * 128 + col) * KTOT + r0 + g * 4;
#pragma unroll
  for (int mt = 0; mt < 4; ++mt)
    *reinterpret_cast<f32x4*>(pp + mt * 16) = acc[mt];
}

// Combine the 2 K-partials + epilogue, separate halves.
// lo = cols 0-63, hi = 64-127. C raw -> optional bt (bf16 transposed), optional
// out write at column base (scaled, optional add for lo, optional accumulate).
__global__ __launch_bounds__(256) void reduce_sep(
    const float* __restrict__ part, float* __restrict__ out,
    const float* s_lo_p, const float* s_hi_p,
    const float* __restrict__ add_ptr, const float* add_s_p,
    __hip_bfloat16* bt_lo, __hip_bfloat16* bt_hi,
    int base_lo, int base_hi, int accum) {
  const int r0 = blockIdx.x * 64;
  const int t = threadIdx.x;
  const int col = t & 127;
  const int rbase = r0 + (t >> 7) * 32;
  const float* p0 = part + (size_t)col * KTOT + rbase;
  const float* p1 = p0 + (size_t)128 * KTOT;
  const bool hi = col >= 64;
  const int col64 = hi ? col - 64 : col;
  __hip_bfloat16* bt = hi ? bt_hi : bt_lo;
  const int obase = hi ? base_hi : base_lo;
  const float s = hi ? (s_hi_p ? *s_hi_p : 0.f) : (s_lo_p ? *s_lo_p : 0.f);
  const float was = add_s_p ? *add_s_p : 0.f;
#pragma unroll
  for (int i = 0; i < 8; ++i) {
    f32x4 c = *reinterpret_cast<const f32x4*>(p0 + 4 * i) +
              *reinterpret_cast<const f32x4*>(p1 + 4 * i);
    if (bt)
      *reinterpret_cast<uint2*>((unsigned short*)bt + (size_t)col64 * KTOT + rbase + 4 * i) =
          pack4(c);
    if (obase >= 0) {
#pragma unroll
      for (int j = 0; j < 4; ++j) {
        int row = rbase + 4 * i + j;
        float v = s * c[j];
        if (add_ptr && !hi) v = fmaf(was, add_ptr[(size_t)row * 64 + col64], v);
        if (accum) v += out[(size_t)row * 128 + obase + col64];
        out[(size_t)row * 128 + obase + col64] = v;
      }
    }
  }
}

// Combine partials + cross-half epilogue: out[:,64+c] = s_lo*lo + s_hi*hi,
// bt_lo = raw lo (bf16 transposed).
__global__ __launch_bounds__(256) void reduce_comb(
    const float* __restrict__ part, float* __restrict__ out,
    const float* s_lo_p, const float* s_hi_p, __hip_bfloat16* bt_lo) {
  const int r0 = blockIdx.x * 64;
  const int t = threadIdx.x;
  const int c = t & 63;
  const int rbase = r0 + (t >> 6) * 16;
  const float* pl0 = part + (size_t)c * KTOT + rbase;
  const float* pl1 = pl0 + (size_t)128 * KTOT;
  const float* ph0 = part + (size_t)(c + 64) * KTOT + rbase;
  const float* ph1 = ph0 + (size_t)128 * KTOT;
  const float sl = *s_lo_p, sh = *s_hi_p;
#pragma unroll
  for (int i = 0; i < 4; ++i) {
    f32x4 lo = *reinterpret_cast<const f32x4*>(pl0 + 4 * i) +
               *reinterpret_cast<const f32x4*>(pl1 + 4 * i);
    f32x4 hv = *reinterpret_cast<const f32x4*>(ph0 + 4 * i) +
               *reinterpret_cast<const f32x4*>(ph1 + 4 * i);
    *reinterpret_cast<uint2*>((unsigned short*)bt_lo + (size_t)c * KTOT + rbase + 4 * i) =
        pack4(lo);
#pragma unroll
    for (int j = 0; j < 4; ++j) {
      int row = rbase + 4 * i + j;
      out[(size_t)row * 128 + 64 + c] = sl * lo[j] + sh * hv[j];
    }
  }
}

extern "C" void kernel_launch(void* const* d_in, const int* in_sizes, int n_in,
                              void* d_out, int out_size, void* d_ws, size_t ws_size,
                              hipStream_t stream) {
  const float* A_p = (const float*)d_in[0];
  const float* A_n = (const float*)d_in[1];
  const float* x_p = (const float*)d_in[2];
  const float* x_n = (const float*)d_in[3];
  const float* w_p = (const float*)d_in[4];  // [3]
  const float* w_n = (const float*)d_in[5];  // [3]
  float* out = (float*)d_out;                // [8192][128]

  // ws layout (13 MiB):
  //   BTbig [192][8192] bf16: rows 0-63 x_p^T, 64-127 x_n^T, 128-191 Y1^T
  //   B3T   [128][8192] bf16: rows 0-63 P1^T, 64-127 T1^T
  //   part  [2][128][8192] f32: K-split raw partials (reused per GEMM)
  __hip_bfloat16* BTbig = (__hip_bfloat16*)d_ws;
  __hip_bfloat16* B3T = BTbig + (size_t)192 * KTOT;
  float* part = (float*)(B3T + (size_t)128 * KTOT);

  xpose_f32_bf16<<<128, 256, 0, stream>>>(x_p, BTbig);
  xpose_f32_bf16<<<128, 256, 0, stream>>>(x_n, BTbig + (size_t)64 * KTOT);

  // G1: [P1|Y1] = A_p @ [x_p|x_n]
  gemm_part<<<256, 512, 0, stream>>>(A_p, BTbig, part);
  // out[:,0:64] = wp0*x_p + wp1*P1; emit P1^T -> B3T[0:64], Y1^T -> BTbig[128:192]
  reduce_sep<<<128, 256, 0, stream>>>(part, out, w_p + 1, nullptr, x_p, w_p + 0,
                                      B3T, BTbig + (size_t)128 * KTOT, 0, -1, 0);

  // G2': [T1|T3] = A_n @ [x_n|Y1]
  gemm_part<<<256, 512, 0, stream>>>(A_n, BTbig + (size_t)64 * KTOT, part);
  // out[:,64:128] = wn0*T1 + wn2*T3; emit T1^T -> B3T[64:128]
  reduce_comb<<<128, 256, 0, stream>>>(part, out, w_n + 0, w_n + 2,
                                       B3T + (size_t)64 * KTOT);

  // G3: [P2|T2] = A_p @ [P1|T1]
  gemm_part<<<256, 512, 0, stream>>>(A_p, B3T, part);
  // out[:,0:64] += wp2*P2; out[:,64:128] += wn1*T2
  reduce_sep<<<128, 256, 0, stream>>>(part, out, w_p + 2, w_n + 1, nullptr, nullptr,
                                      nullptr, nullptr, 0, 64, 1);
}